// Round 20
// baseline (807.816 us; speedup 1.0000x reference)
//
#include <hip/hip_runtime.h>

#define HID   100
#define TT    1024
#define BPW   16   // batches per WG (= MFMA N)
#define WPL   16   // WGs per LSTM -> grid 48
#define NTHR  512  // 8 waves
#define NKK   4    // K = 128: 4 chunks of 32
#define CHUNK 64   // x staging chunk (steps)

typedef _Float16 f16x8 __attribute__((ext_vector_type(8)));
typedef float    f32x4 __attribute__((ext_vector_type(4)));

#if __has_builtin(__builtin_amdgcn_exp2f)
#define EXP2(x) __builtin_amdgcn_exp2f(x)
#else
#define EXP2(x) exp2f(x)
#endif
#if __has_builtin(__builtin_amdgcn_rcpf)
#define RCP(x) __builtin_amdgcn_rcpf(x)
#else
#define RCP(x) (1.f / (x))
#endif

// v19 = v18 (723us, passing) with a shorter per-step critical path:
//  - 2-deep MFMA chains: each tile's K-accum split kk01/kk23 into partial
//    accs (two asm blocks), v_add after -> dependent depth 4 -> 2.
//  - wave 0's tile 24 merged into the main blocks (no serial 2nd block).
//  - block1 consumes only b0,b1 -> compiler can start at lgkmcnt(2).
//  - wave 7's x-insert moved BEFORE its MFMA phase (overlaps read-wait,
//    de-straggles the end-of-step barrier).
// W stays in compiler-tracked AGPRs ("+a" pins + "a" asm inputs, s_nop
// hazard fences) -- R18-verified.
__global__ __launch_bounds__(NTHR, 2) void lstm3_kernel(
    const float* __restrict__ x1, const float* __restrict__ x2, const float* __restrict__ x3,
    const float* __restrict__ Wih1, const float* __restrict__ Whh1, const float* __restrict__ bi1, const float* __restrict__ bh1,
    const float* __restrict__ Wih2, const float* __restrict__ Whh2, const float* __restrict__ bi2, const float* __restrict__ bh2,
    const float* __restrict__ Wih3, const float* __restrict__ Whh3, const float* __restrict__ bi3, const float* __restrict__ bh3,
    float* __restrict__ hws)
{
    const int wg    = blockIdx.x;
    const int L     = wg / WPL;
    const int bbase = (wg % WPL) * BPW;
    const int tid   = threadIdx.x;

    const float* x   = (L == 0) ? x1   : (L == 1) ? x2   : x3;
    const float* Wih = (L == 0) ? Wih1 : (L == 1) ? Wih2 : Wih3;
    const float* Whh = (L == 0) ? Whh1 : (L == 1) ? Whh2 : Whh3;
    const float* bi  = (L == 0) ? bi1  : (L == 1) ? bi2  : bi3;
    const float* bh  = (L == 0) ? bh1  : (L == 1) ? bh2  : bh3;

    __shared__ f16x8 Wfq[25 * NKK * 64];      // 102,400 B (staging; cold after init)
    __shared__ f16x8 hfq[2][NKK][64];         //   8,192 B (buf, kk, lane)
    __shared__ f32x4 xch[2][CHUNK][BPW];      //  32,768 B -> total 143,360 B

    // ---- one-time W staging, fragment order, exp2-scale folded ----
    for (int idx = tid; idx < 25 * NKK * 64; idx += NTHR) {
        const int l   = idx & 63;
        const int kkt = idx >> 6;
        const int kk  = kkt & 3, t = kkt >> 2;
        const int m   = l & 15, g = l >> 4;
        const int gate = m & 3;
        const int srow = gate * 100 + 4 * t + (m >> 2);
        const float scl = (gate == 2) ? -2.885390082f : -1.442695041f;
        f16x8 q;
#pragma unroll
        for (int j = 0; j < 8; ++j) {
            const int ke = kk * 32 + g * 8 + j;
            float v = 0.f;
            if (ke < 100)       v = Whh[(size_t)srow * HID + ke];
            else if (ke < 104)  v = Wih[(size_t)srow * 4 + (ke - 100)];
            else if (ke == 104) v = bi[srow] + bh[srow];
            q[j] = (_Float16)(v * scl);
        }
        Wfq[idx] = q;
    }
    // ---- h buffers zero ----
    for (int i = tid; i < 2 * NKK * 64; i += NTHR) {
        f16x8 z;
#pragma unroll
        for (int j = 0; j < 8; ++j) z[j] = (_Float16)0.f;
        ((f16x8*)hfq)[i] = z;
    }
    // ---- x chunk 0 (step-major) ----
    for (int q = tid; q < CHUNK * BPW; q += NTHR) {
        const int s = q >> 4, b = q & 15;
        xch[0][s][b] = *(const f32x4*)(x + ((size_t)(bbase + b) * TT + s) * 4);
    }
    __syncthreads();
    if (tid < 32) {  // bias column ke=104 -> kk=3, word 16+bat, j=0 (both bufs)
        const int buf = tid >> 4, b = tid & 15;
        ((_Float16*)&hfq[buf][3][16 + b])[0] = (_Float16)1.f;
    }
    if (tid < 16) {  // x_0: ke=100..103 -> kk=3, word bat, j=4..7 (buf 0)
        const int b = tid;
        const f32x4 xv = xch[0][0][b];
        _Float16* pH = (_Float16*)&hfq[0][3][b];
#pragma unroll
        for (int j = 0; j < 4; ++j) pH[4 + j] = (_Float16)xv[j];
    }
    __syncthreads();

    const int wave = tid >> 6, lane = tid & 63;
    const int bat  = lane & 15, g16 = lane >> 4;

    const int  t0 = wave, t1 = wave + 8, t2 = wave + 16;
    const bool v3 = (wave == 0);
    const int  t3 = 24;

    // ---- W fragments -> compiler-tracked AGPR residents ----
    const f16x8* wp0 = &Wfq[t0 * NKK * 64 + lane];
    const f16x8* wp1 = &Wfq[t1 * NKK * 64 + lane];
    const f16x8* wp2 = &Wfq[t2 * NKK * 64 + lane];
    const f16x8* wp3 = &Wfq[t3 * NKK * 64 + lane];
    f16x8 W00 = wp0[0], W01 = wp0[64], W02 = wp0[128], W03 = wp0[192];
    f16x8 W10 = wp1[0], W11 = wp1[64], W12 = wp1[128], W13 = wp1[192];
    f16x8 W20 = wp2[0], W21 = wp2[64], W22 = wp2[128], W23 = wp2[192];
    f16x8 W30 = wp3[0], W31 = wp3[64], W32 = wp3[128], W33 = wp3[192];
    asm volatile("" : "+a"(W00), "+a"(W01), "+a"(W02), "+a"(W03));
    asm volatile("" : "+a"(W10), "+a"(W11), "+a"(W12), "+a"(W13));
    asm volatile("" : "+a"(W20), "+a"(W21), "+a"(W22), "+a"(W23));
    asm volatile("" : "+a"(W30), "+a"(W31), "+a"(W32), "+a"(W33));

    float cc0 = 0.f, cc1 = 0.f, cc2 = 0.f, cc3 = 0.f;
    float hh0 = 0.f, hh1 = 0.f, hh2 = 0.f, hh3 = 0.f;

    const int c0 = 4 * t0 + g16, c1 = 4 * t1 + g16, c2 = 4 * t2 + g16, c3 = 4 * t3 + g16;

    // hoisted, parity-constant pointers
    char* const hbase = (char*)hfq;
#define CELL_OFF(C) ((size_t)(((C) >> 5) * 1024 + (((((C) & 31) >> 3) << 4) + bat) * 16 + ((C) & 7) * 2))
    _Float16* const p0E = (_Float16*)(hbase + 4096 + CELL_OFF(c0));  // even step writes buf1
    _Float16* const p1E = (_Float16*)(hbase + 4096 + CELL_OFF(c1));
    _Float16* const p2E = (_Float16*)(hbase + 4096 + CELL_OFF(c2));
    _Float16* const p3E = (_Float16*)(hbase + 4096 + CELL_OFF(c3));
    _Float16* const p0O = (_Float16*)(hbase + CELL_OFF(c0));         // odd step writes buf0
    _Float16* const p1O = (_Float16*)(hbase + CELL_OFF(c1));
    _Float16* const p2O = (_Float16*)(hbase + CELL_OFF(c2));
    _Float16* const p3O = (_Float16*)(hbase + CELL_OFF(c3));
#undef CELL_OFF
    const f16x8* const hbE = &hfq[0][0][lane];   // even step reads buf0
    const f16x8* const hbO = &hfq[1][0][lane];   // odd step reads buf1
    _Float16* const xiE = (_Float16*)(hbase + 4096 + 3 * 1024 + lane * 16);  // x-insert even -> buf1
    _Float16* const xiO = (_Float16*)(hbase + 3 * 1024 + lane * 16);         // x-insert odd  -> buf0

#define UPDATE(AV, CC, HH, PH) do {                                          \
        const float si = RCP(1.f + EXP2(AV[0]));                             \
        const float sf = RCP(1.f + EXP2(AV[1]));                             \
        const float tg = 2.f * RCP(1.f + EXP2(AV[2])) - 1.f;                 \
        const float so = RCP(1.f + EXP2(AV[3]));                             \
        CC = sf * CC + si * tg;                                              \
        const float tc = 2.f * RCP(1.f + EXP2(CC * -2.885390082f)) - 1.f;    \
        HH = so * tc;                                                        \
        *(PH) = (_Float16)HH;                                                \
    } while (0)

#define STEP_BODY(HB, P0, P1, P2, P3, XI, ST) do {                           \
        /* wave 7: x-insert FIRST (depends only on xch; overlaps others'     \
           read-wait instead of extending wave 7's tail) */                  \
        if (wave == 7 && lane < 16) {                                        \
            const int sp = (ST) + 1;                                         \
            const f32x4 xv = xch[(sp >> 6) & 1][sp & (CHUNK - 1)][lane];     \
            _Float16* pX = (XI);                                             \
            pX[4] = (_Float16)xv[0]; pX[5] = (_Float16)xv[1];                \
            pX[6] = (_Float16)xv[2]; pX[7] = (_Float16)xv[3];                \
        }                                                                    \
        const f16x8 b0 = (HB)[0], b1 = (HB)[64];                             \
        const f16x8 b2 = (HB)[128], b3 = (HB)[192];                          \
        f32x4 z = {0.f, 0.f, 0.f, 0.f};                                      \
        f32x4 A0a = z, A1a = z, A2a = z, A0b = z, A1b = z, A2b = z;          \
        if (v3) {                                                            \
            f32x4 A3a = z, A3b = z;                                          \
            asm volatile(                                                    \
                "s_nop 2\n\t"                                                \
                "v_mfma_f32_16x16x32_f16 %0, %6, %4, %0\n\t"                 \
                "v_mfma_f32_16x16x32_f16 %1, %8, %4, %1\n\t"                 \
                "v_mfma_f32_16x16x32_f16 %2, %10, %4, %2\n\t"                \
                "v_mfma_f32_16x16x32_f16 %3, %12, %4, %3\n\t"                \
                "v_mfma_f32_16x16x32_f16 %0, %7, %5, %0\n\t"                 \
                "v_mfma_f32_16x16x32_f16 %1, %9, %5, %1\n\t"                 \
                "v_mfma_f32_16x16x32_f16 %2, %11, %5, %2\n\t"                \
                "v_mfma_f32_16x16x32_f16 %3, %13, %5, %3"                    \
                : "+v"(A0a), "+v"(A1a), "+v"(A2a), "+v"(A3a)                 \
                : "v"(b0), "v"(b1),                                          \
                  "a"(W00), "a"(W01), "a"(W10), "a"(W11),                    \
                  "a"(W20), "a"(W21), "a"(W30), "a"(W31));                   \
            asm volatile(                                                    \
                "s_nop 2\n\t"                                                \
                "v_mfma_f32_16x16x32_f16 %0, %6, %4, %0\n\t"                 \
                "v_mfma_f32_16x16x32_f16 %1, %8, %4, %1\n\t"                 \
                "v_mfma_f32_16x16x32_f16 %2, %10, %4, %2\n\t"                \
                "v_mfma_f32_16x16x32_f16 %3, %12, %4, %3\n\t"                \
                "v_mfma_f32_16x16x32_f16 %0, %7, %5, %0\n\t"                 \
                "v_mfma_f32_16x16x32_f16 %1, %9, %5, %1\n\t"                 \
                "v_mfma_f32_16x16x32_f16 %2, %11, %5, %2\n\t"                \
                "v_mfma_f32_16x16x32_f16 %3, %13, %5, %3\n\t"                \
                "s_nop 7\n\t"                                                \
                "s_nop 7"                                                    \
                : "+v"(A0b), "+v"(A1b), "+v"(A2b), "+v"(A3b)                 \
                : "v"(b2), "v"(b3),                                          \
                  "a"(W02), "a"(W03), "a"(W12), "a"(W13),                    \
                  "a"(W22), "a"(W23), "a"(W32), "a"(W33));                   \
            const f32x4 A3 = A3a + A3b;                                      \
            UPDATE(A3, cc3, hh3, P3);                                        \
        } else {                                                             \
            asm volatile(                                                    \
                "s_nop 2\n\t"                                                \
                "v_mfma_f32_16x16x32_f16 %0, %5, %3, %0\n\t"                 \
                "v_mfma_f32_16x16x32_f16 %1, %7, %3, %1\n\t"                 \
                "v_mfma_f32_16x16x32_f16 %2, %9, %3, %2\n\t"                 \
                "v_mfma_f32_16x16x32_f16 %0, %6, %4, %0\n\t"                 \
                "v_mfma_f32_16x16x32_f16 %1, %8, %4, %1\n\t"                 \
                "v_mfma_f32_16x16x32_f16 %2, %10, %4, %2"                    \
                : "+v"(A0a), "+v"(A1a), "+v"(A2a)                            \
                : "v"(b0), "v"(b1),                                          \
                  "a"(W00), "a"(W01), "a"(W10), "a"(W11),                    \
                  "a"(W20), "a"(W21));                                       \
            asm volatile(                                                    \
                "s_nop 2\n\t"                                                \
                "v_mfma_f32_16x16x32_f16 %0, %5, %3, %0\n\t"                 \
                "v_mfma_f32_16x16x32_f16 %1, %7, %3, %1\n\t"                 \
                "v_mfma_f32_16x16x32_f16 %2, %9, %3, %2\n\t"                 \
                "v_mfma_f32_16x16x32_f16 %0, %6, %4, %0\n\t"                 \
                "v_mfma_f32_16x16x32_f16 %1, %8, %4, %1\n\t"                 \
                "v_mfma_f32_16x16x32_f16 %2, %10, %4, %2\n\t"                \
                "s_nop 7\n\t"                                                \
                "s_nop 7"                                                    \
                : "+v"(A0b), "+v"(A1b), "+v"(A2b)                            \
                : "v"(b2), "v"(b3),                                          \
                  "a"(W02), "a"(W03), "a"(W12), "a"(W13),                    \
                  "a"(W22), "a"(W23));                                       \
        }                                                                    \
        const f32x4 A0 = A0a + A0b;                                          \
        const f32x4 A1 = A1a + A1b;                                          \
        const f32x4 A2 = A2a + A2b;                                          \
        UPDATE(A0, cc0, hh0, P0);                                            \
        UPDATE(A1, cc1, hh1, P1);                                            \
        UPDATE(A2, cc2, hh2, P2);                                            \
    } while (0)

#pragma unroll 1
    for (int st = 0; st < TT; st += 2) {
        // even step: read buf0, write buf1
        STEP_BODY(hbE, p0E, p1E, p2E, p3E, xiE, st);
        if (wave == 6 && (st & (CHUNK - 1)) == 0) {   // prefetch next x chunk
            const int nc = (st >> 6) + 1;
            if (nc < TT / CHUNK) {
#pragma unroll
                for (int it = 0; it < (CHUNK * BPW) / 64; ++it) {
                    const int q = it * 64 + lane;
                    const int s = q >> 4, b = q & 15;
                    xch[nc & 1][s][b] =
                        *(const f32x4*)(x + ((size_t)(bbase + b) * TT + nc * CHUNK + s) * 4);
                }
            }
        }
        __syncthreads();
        // odd step: read buf1, write buf0
        STEP_BODY(hbO, p0O, p1O, p2O, p3O, xiO, st + 1);
        __syncthreads();
    }
#undef STEP_BODY
#undef UPDATE

    // ---- final h -> workspace [b_global][300], column L*100 + cell ----
    {
        const size_t ob = (size_t)(bbase + bat) * 300 + L * HID;
        hws[ob + c0] = hh0;
        hws[ob + c1] = hh1;
        hws[ob + c2] = hh2;
        if (v3) hws[ob + c3] = hh3;
    }
}

// out[b][o] = relu(fc_b[o] + sum_j h[b][j] * fc_W[o][j]),  j < 300, o < 12
__global__ __launch_bounds__(64, 1) void fc_kernel(
    const float* __restrict__ hws, const float* __restrict__ fcW,
    const float* __restrict__ fcb, float* __restrict__ out)
{
    const int b = blockIdx.x, lane = threadIdx.x;
    float hv[5];
#pragma unroll
    for (int c = 0; c < 5; c++) {
        const int j = lane + 64 * c;
        hv[c] = (j < 300) ? hws[b * 300 + j] : 0.f;
    }
#pragma unroll
    for (int o = 0; o < 12; o++) {
        float a = 0.f;
#pragma unroll
        for (int c = 0; c < 5; c++) {
            const int j = lane + 64 * c;
            const float wv = (j < 300) ? fcW[o * 300 + j] : 0.f;
            a += hv[c] * wv;
        }
#pragma unroll
        for (int off = 32; off > 0; off >>= 1) a += __shfl_xor(a, off, 64);
        if (lane == 0) out[b * 12 + o] = fmaxf(a + fcb[o], 0.f);
    }
}

extern "C" void kernel_launch(void* const* d_in, const int* in_sizes, int n_in,
                              void* d_out, int out_size, void* d_ws, size_t ws_size,
                              hipStream_t stream)
{
    const float* x1   = (const float*)d_in[0];
    const float* x2   = (const float*)d_in[1];
    const float* x3   = (const float*)d_in[2];
    const float* Wih1 = (const float*)d_in[3];
    const float* Whh1 = (const float*)d_in[4];
    const float* bi1  = (const float*)d_in[5];
    const float* bh1  = (const float*)d_in[6];
    const float* Wih2 = (const float*)d_in[7];
    const float* Whh2 = (const float*)d_in[8];
    const float* bi2  = (const float*)d_in[9];
    const float* bh2  = (const float*)d_in[10];
    const float* Wih3 = (const float*)d_in[11];
    const float* Whh3 = (const float*)d_in[12];
    const float* bi3  = (const float*)d_in[13];
    const float* bh3  = (const float*)d_in[14];
    const float* fcW  = (const float*)d_in[15];
    const float* fcb  = (const float*)d_in[16];

    float* hws = (float*)d_ws;  // 256*300 floats = 300 KiB

    lstm3_kernel<<<3 * WPL, NTHR, 0, stream>>>(x1, x2, x3,
                                               Wih1, Whh1, bi1, bh1,
                                               Wih2, Whh2, bi2, bh2,
                                               Wih3, Whh3, bi3, bh3, hws);
    fc_kernel<<<256, 64, 0, stream>>>(hws, fcW, fcb, (float*)d_out);
}

// Round 21
// 685.596 us; speedup vs baseline: 1.1783x; 1.1783x over previous
//
#include <hip/hip_runtime.h>

#define HID   100
#define TT    1024
#define BPW   16   // batches per WG (= MFMA N)
#define WPL   16   // WGs per LSTM -> grid 48
#define NTHR  512  // 8 waves
#define NKK   4    // K = 128: 4 chunks of 32
#define CHUNK 64   // x staging chunk (steps)

typedef _Float16 f16x8 __attribute__((ext_vector_type(8)));
typedef float    f32x4 __attribute__((ext_vector_type(4)));

#if __has_builtin(__builtin_amdgcn_exp2f)
#define EXP2(x) __builtin_amdgcn_exp2f(x)
#else
#define EXP2(x) exp2f(x)
#endif
#if __has_builtin(__builtin_amdgcn_rcpf)
#define RCP(x) __builtin_amdgcn_rcpf(x)
#else
#define RCP(x) (1.f / (x))
#endif

// v20 = v18 (723us, verified) minus per-step instructions:
//  - acc zero-init v_movs (12/wave/step) removed: first MFMA of each chain
//    takes a loop-invariant zero4 register as C ("=&v" outputs).
//  - cc carried pre-scaled by -2log2e: the serial cc->mul->exp2 constant
//    multiply folds into the (parallel) tg term via one fma.
//  - wave 7's x-insert issued FIRST in the step (depends only on xch) ->
//    de-straggles the end-of-step barrier.
// R19 lesson: at 2 waves/SIMD lockstep, step time ~ instructions on the
// path (~13 cyc/instr marginal); only strictly-removing edits pay.
__global__ __launch_bounds__(NTHR, 2) void lstm3_kernel(
    const float* __restrict__ x1, const float* __restrict__ x2, const float* __restrict__ x3,
    const float* __restrict__ Wih1, const float* __restrict__ Whh1, const float* __restrict__ bi1, const float* __restrict__ bh1,
    const float* __restrict__ Wih2, const float* __restrict__ Whh2, const float* __restrict__ bi2, const float* __restrict__ bh2,
    const float* __restrict__ Wih3, const float* __restrict__ Whh3, const float* __restrict__ bi3, const float* __restrict__ bh3,
    float* __restrict__ hws)
{
    const int wg    = blockIdx.x;
    const int L     = wg / WPL;
    const int bbase = (wg % WPL) * BPW;
    const int tid   = threadIdx.x;

    const float* x   = (L == 0) ? x1   : (L == 1) ? x2   : x3;
    const float* Wih = (L == 0) ? Wih1 : (L == 1) ? Wih2 : Wih3;
    const float* Whh = (L == 0) ? Whh1 : (L == 1) ? Whh2 : Whh3;
    const float* bi  = (L == 0) ? bi1  : (L == 1) ? bi2  : bi3;
    const float* bh  = (L == 0) ? bh1  : (L == 1) ? bh2  : bh3;

    __shared__ f16x8 Wfq[25 * NKK * 64];      // 102,400 B (staging; cold after init)
    __shared__ f16x8 hfq[2][NKK][64];         //   8,192 B (buf, kk, lane)
    __shared__ f32x4 xch[2][CHUNK][BPW];      //  32,768 B -> total 143,360 B

    // ---- one-time W staging, fragment order, exp2-scale folded ----
    for (int idx = tid; idx < 25 * NKK * 64; idx += NTHR) {
        const int l   = idx & 63;
        const int kkt = idx >> 6;
        const int kk  = kkt & 3, t = kkt >> 2;
        const int m   = l & 15, g = l >> 4;
        const int gate = m & 3;
        const int srow = gate * 100 + 4 * t + (m >> 2);
        const float scl = (gate == 2) ? -2.885390082f : -1.442695041f;
        f16x8 q;
#pragma unroll
        for (int j = 0; j < 8; ++j) {
            const int ke = kk * 32 + g * 8 + j;
            float v = 0.f;
            if (ke < 100)       v = Whh[(size_t)srow * HID + ke];
            else if (ke < 104)  v = Wih[(size_t)srow * 4 + (ke - 100)];
            else if (ke == 104) v = bi[srow] + bh[srow];
            q[j] = (_Float16)(v * scl);
        }
        Wfq[idx] = q;
    }
    // ---- h buffers zero ----
    for (int i = tid; i < 2 * NKK * 64; i += NTHR) {
        f16x8 z;
#pragma unroll
        for (int j = 0; j < 8; ++j) z[j] = (_Float16)0.f;
        ((f16x8*)hfq)[i] = z;
    }
    // ---- x chunk 0 (step-major) ----
    for (int q = tid; q < CHUNK * BPW; q += NTHR) {
        const int s = q >> 4, b = q & 15;
        xch[0][s][b] = *(const f32x4*)(x + ((size_t)(bbase + b) * TT + s) * 4);
    }
    __syncthreads();
    if (tid < 32) {  // bias column ke=104 -> kk=3, word 16+bat, j=0 (both bufs)
        const int buf = tid >> 4, b = tid & 15;
        ((_Float16*)&hfq[buf][3][16 + b])[0] = (_Float16)1.f;
    }
    if (tid < 16) {  // x_0: ke=100..103 -> kk=3, word bat, j=4..7 (buf 0)
        const int b = tid;
        const f32x4 xv = xch[0][0][b];
        _Float16* pH = (_Float16*)&hfq[0][3][b];
#pragma unroll
        for (int j = 0; j < 4; ++j) pH[4 + j] = (_Float16)xv[j];
    }
    __syncthreads();

    const int wave = tid >> 6, lane = tid & 63;
    const int bat  = lane & 15, g16 = lane >> 4;

    const int  t0 = wave, t1 = wave + 8, t2 = wave + 16;
    const bool v3 = (wave == 0);
    const int  t3 = 24;

    // ---- W fragments -> compiler-tracked AGPR residents ----
    const f16x8* wp0 = &Wfq[t0 * NKK * 64 + lane];
    const f16x8* wp1 = &Wfq[t1 * NKK * 64 + lane];
    const f16x8* wp2 = &Wfq[t2 * NKK * 64 + lane];
    const f16x8* wp3 = &Wfq[t3 * NKK * 64 + lane];
    f16x8 W00 = wp0[0], W01 = wp0[64], W02 = wp0[128], W03 = wp0[192];
    f16x8 W10 = wp1[0], W11 = wp1[64], W12 = wp1[128], W13 = wp1[192];
    f16x8 W20 = wp2[0], W21 = wp2[64], W22 = wp2[128], W23 = wp2[192];
    f16x8 W30 = wp3[0], W31 = wp3[64], W32 = wp3[128], W33 = wp3[192];
    asm volatile("" : "+a"(W00), "+a"(W01), "+a"(W02), "+a"(W03));
    asm volatile("" : "+a"(W10), "+a"(W11), "+a"(W12), "+a"(W13));
    asm volatile("" : "+a"(W20), "+a"(W21), "+a"(W22), "+a"(W23));
    asm volatile("" : "+a"(W30), "+a"(W31), "+a"(W32), "+a"(W33));

    // loop-invariant zero C-operand (removes 12 v_mov acc-inits per step)
    f32x4 zero4 = {0.f, 0.f, 0.f, 0.f};
    asm volatile("" : "+v"(zero4));

    float cc0 = 0.f, cc1 = 0.f, cc2 = 0.f, cc3 = 0.f;   // carried as -2log2e * c
    float hh0 = 0.f, hh1 = 0.f, hh2 = 0.f, hh3 = 0.f;

    const int c0 = 4 * t0 + g16, c1 = 4 * t1 + g16, c2 = 4 * t2 + g16, c3 = 4 * t3 + g16;

    // hoisted, parity-constant pointers
    char* const hbase = (char*)hfq;
#define CELL_OFF(C) ((size_t)(((C) >> 5) * 1024 + (((((C) & 31) >> 3) << 4) + bat) * 16 + ((C) & 7) * 2))
    _Float16* const p0E = (_Float16*)(hbase + 4096 + CELL_OFF(c0));  // even step writes buf1
    _Float16* const p1E = (_Float16*)(hbase + 4096 + CELL_OFF(c1));
    _Float16* const p2E = (_Float16*)(hbase + 4096 + CELL_OFF(c2));
    _Float16* const p3E = (_Float16*)(hbase + 4096 + CELL_OFF(c3));
    _Float16* const p0O = (_Float16*)(hbase + CELL_OFF(c0));         // odd step writes buf0
    _Float16* const p1O = (_Float16*)(hbase + CELL_OFF(c1));
    _Float16* const p2O = (_Float16*)(hbase + CELL_OFF(c2));
    _Float16* const p3O = (_Float16*)(hbase + CELL_OFF(c3));
#undef CELL_OFF
    const f16x8* const hbE = &hfq[0][0][lane];   // even step reads buf0
    const f16x8* const hbO = &hfq[1][0][lane];   // odd step reads buf1
    _Float16* const xiE = (_Float16*)(hbase + 4096 + 3 * 1024 + lane * 16);  // x-insert even -> buf1
    _Float16* const xiO = (_Float16*)(hbase + 3 * 1024 + lane * 16);         // x-insert odd  -> buf0

    // cc is carried pre-scaled: cc_s = -2log2e * c. tg_s = -2log2e * tanh(g)
    // = fma(-5.7708, rcp, 2.8854). tanh(c) = 2*rcp(1+exp2(cc_s)) - 1.
#define UPDATE(AV, CC, HH, PH) do {                                          \
        const float si = RCP(1.f + EXP2(AV[0]));                             \
        const float sf = RCP(1.f + EXP2(AV[1]));                             \
        const float tgs = -5.770780163f * RCP(1.f + EXP2(AV[2])) + 2.885390082f; \
        const float so = RCP(1.f + EXP2(AV[3]));                             \
        CC = sf * CC + si * tgs;                                             \
        const float tc = 2.f * RCP(1.f + EXP2(CC)) - 1.f;                    \
        HH = so * tc;                                                        \
        *(PH) = (_Float16)HH;                                                \
    } while (0)

#define STEP_BODY(HB, P0, P1, P2, P3, XI, ST) do {                           \
        /* wave 7: x-insert FIRST (depends only on xch; overlaps others'     \
           read-wait instead of extending wave 7's tail) */                  \
        if (wave == 7 && lane < 16) {                                        \
            const int sp = (ST) + 1;                                         \
            const f32x4 xv = xch[(sp >> 6) & 1][sp & (CHUNK - 1)][lane];     \
            _Float16* pX = (XI);                                             \
            pX[4] = (_Float16)xv[0]; pX[5] = (_Float16)xv[1];                \
            pX[6] = (_Float16)xv[2]; pX[7] = (_Float16)xv[3];                \
        }                                                                    \
        const f16x8 b0 = (HB)[0], b1 = (HB)[64];                             \
        const f16x8 b2 = (HB)[128], b3 = (HB)[192];                          \
        f32x4 A0, A1, A2;                                                    \
        asm volatile(                                                        \
            "s_nop 2\n\t"                                                    \
            "v_mfma_f32_16x16x32_f16 %0, %7, %3, %19\n\t"                    \
            "v_mfma_f32_16x16x32_f16 %1, %11, %3, %19\n\t"                   \
            "v_mfma_f32_16x16x32_f16 %2, %15, %3, %19\n\t"                   \
            "v_mfma_f32_16x16x32_f16 %0, %8, %4, %0\n\t"                     \
            "v_mfma_f32_16x16x32_f16 %1, %12, %4, %1\n\t"                    \
            "v_mfma_f32_16x16x32_f16 %2, %16, %4, %2\n\t"                    \
            "v_mfma_f32_16x16x32_f16 %0, %9, %5, %0\n\t"                     \
            "v_mfma_f32_16x16x32_f16 %1, %13, %5, %1\n\t"                    \
            "v_mfma_f32_16x16x32_f16 %2, %17, %5, %2\n\t"                    \
            "v_mfma_f32_16x16x32_f16 %0, %10, %6, %0\n\t"                    \
            "v_mfma_f32_16x16x32_f16 %1, %14, %6, %1\n\t"                    \
            "v_mfma_f32_16x16x32_f16 %2, %18, %6, %2\n\t"                    \
            "s_nop 7\n\t"                                                    \
            "s_nop 7"                                                        \
            : "=&v"(A0), "=&v"(A1), "=&v"(A2)                                \
            : "v"(b0), "v"(b1), "v"(b2), "v"(b3),                            \
              "a"(W00), "a"(W01), "a"(W02), "a"(W03),                        \
              "a"(W10), "a"(W11), "a"(W12), "a"(W13),                        \
              "a"(W20), "a"(W21), "a"(W22), "a"(W23),                        \
              "v"(zero4));                                                   \
        UPDATE(A0, cc0, hh0, P0);                                            \
        UPDATE(A1, cc1, hh1, P1);                                            \
        UPDATE(A2, cc2, hh2, P2);                                            \
        if (v3) {                                                            \
            f32x4 A3;                                                        \
            asm volatile(                                                    \
                "s_nop 2\n\t"                                                \
                "v_mfma_f32_16x16x32_f16 %0, %5, %1, %9\n\t"                 \
                "v_mfma_f32_16x16x32_f16 %0, %6, %2, %0\n\t"                 \
                "v_mfma_f32_16x16x32_f16 %0, %7, %3, %0\n\t"                 \
                "v_mfma_f32_16x16x32_f16 %0, %8, %4, %0\n\t"                 \
                "s_nop 7\n\t"                                                \
                "s_nop 7"                                                    \
                : "=&v"(A3)                                                  \
                : "v"(b0), "v"(b1), "v"(b2), "v"(b3),                        \
                  "a"(W30), "a"(W31), "a"(W32), "a"(W33),                    \
                  "v"(zero4));                                               \
            UPDATE(A3, cc3, hh3, P3);                                        \
        }                                                                    \
    } while (0)

#pragma unroll 1
    for (int st = 0; st < TT; st += 2) {
        // even step: read buf0, write buf1
        STEP_BODY(hbE, p0E, p1E, p2E, p3E, xiE, st);
        if (wave == 6 && (st & (CHUNK - 1)) == 0) {   // prefetch next x chunk
            const int nc = (st >> 6) + 1;
            if (nc < TT / CHUNK) {
#pragma unroll
                for (int it = 0; it < (CHUNK * BPW) / 64; ++it) {
                    const int q = it * 64 + lane;
                    const int s = q >> 4, b = q & 15;
                    xch[nc & 1][s][b] =
                        *(const f32x4*)(x + ((size_t)(bbase + b) * TT + nc * CHUNK + s) * 4);
                }
            }
        }
        __syncthreads();
        // odd step: read buf1, write buf0
        STEP_BODY(hbO, p0O, p1O, p2O, p3O, xiO, st + 1);
        __syncthreads();
    }
#undef STEP_BODY
#undef UPDATE

    // ---- final h -> workspace [b_global][300], column L*100 + cell ----
    {
        const size_t ob = (size_t)(bbase + bat) * 300 + L * HID;
        hws[ob + c0] = hh0;
        hws[ob + c1] = hh1;
        hws[ob + c2] = hh2;
        if (v3) hws[ob + c3] = hh3;
    }
}

// out[b][o] = relu(fc_b[o] + sum_j h[b][j] * fc_W[o][j]),  j < 300, o < 12
__global__ __launch_bounds__(64, 1) void fc_kernel(
    const float* __restrict__ hws, const float* __restrict__ fcW,
    const float* __restrict__ fcb, float* __restrict__ out)
{
    const int b = blockIdx.x, lane = threadIdx.x;
    float hv[5];
#pragma unroll
    for (int c = 0; c < 5; c++) {
        const int j = lane + 64 * c;
        hv[c] = (j < 300) ? hws[b * 300 + j] : 0.f;
    }
#pragma unroll
    for (int o = 0; o < 12; o++) {
        float a = 0.f;
#pragma unroll
        for (int c = 0; c < 5; c++) {
            const int j = lane + 64 * c;
            const float wv = (j < 300) ? fcW[o * 300 + j] : 0.f;
            a += hv[c] * wv;
        }
#pragma unroll
        for (int off = 32; off > 0; off >>= 1) a += __shfl_xor(a, off, 64);
        if (lane == 0) out[b * 12 + o] = fmaxf(a + fcb[o], 0.f);
    }
}

extern "C" void kernel_launch(void* const* d_in, const int* in_sizes, int n_in,
                              void* d_out, int out_size, void* d_ws, size_t ws_size,
                              hipStream_t stream)
{
    const float* x1   = (const float*)d_in[0];
    const float* x2   = (const float*)d_in[1];
    const float* x3   = (const float*)d_in[2];
    const float* Wih1 = (const float*)d_in[3];
    const float* Whh1 = (const float*)d_in[4];
    const float* bi1  = (const float*)d_in[5];
    const float* bh1  = (const float*)d_in[6];
    const float* Wih2 = (const float*)d_in[7];
    const float* Whh2 = (const float*)d_in[8];
    const float* bi2  = (const float*)d_in[9];
    const float* bh2  = (const float*)d_in[10];
    const float* Wih3 = (const float*)d_in[11];
    const float* Whh3 = (const float*)d_in[12];
    const float* bi3  = (const float*)d_in[13];
    const float* bh3  = (const float*)d_in[14];
    const float* fcW  = (const float*)d_in[15];
    const float* fcb  = (const float*)d_in[16];

    float* hws = (float*)d_ws;  // 256*300 floats = 300 KiB

    lstm3_kernel<<<3 * WPL, NTHR, 0, stream>>>(x1, x2, x3,
                                               Wih1, Whh1, bi1, bh1,
                                               Wih2, Whh2, bi2, bh2,
                                               Wih3, Whh3, bi3, bh3, hws);
    fc_kernel<<<256, 64, 0, stream>>>(hws, fcW, fcb, (float*)d_out);
}